// Round 12
// baseline (499.016 us; speedup 1.0000x reference)
//
#include <hip/hip_runtime.h>
#include <hip/hip_bf16.h>
#include <math.h>

#define E_DIM 512
#define H_DIM 1024
#define V_DIM 50257
#define NSTEPS 19
#define NB_F32 1024      // fp32 logits blocks (4 waves each)
#define NB_LOG 256       // int8 scan blocks (16 waves each) -> 4096 waves, 1 block/CU
#define RPW 13           // rows per wave (4096*13 = 53248 >= V)
#define RPB 208          // rows per scan block (16*13)
#define VPAD 53248       // padded row count
#define NB_GATES 256
#define BL_CAP 192
#define CAND_CAP 1024

// ---- workspace layout (bytes), NO overlaps, 16B-aligned ----
#define OFF_X      0          // 512 f
#define OFF_H      4096       // 1024 f
#define OFF_C      8192       // 1024 f (ping)
#define OFF_C2     12288      // 1024 f (pong)
#define OFF_GATES  16384      // 4096 f (ends 32768)
#define OFF_PART   33024      // 1024 u64 (ends 41216)
#define OFF_PBLOCK 41216      // 256 float2 (ends 43264)
#define OFF_SNB    49152      // VPAD float4 {scale, nrm, bias, 0} (ends 901120)
#define OFF_LE     901120     // VPAD float2 {L, e} (ends 1327104)
#define OFF_WBI    1327104    // int8 W_lin, VPAD*1024 B (ends 55853056)
#define WS_NEEDED  55853056ull

__device__ inline unsigned fmap(float f) {
    unsigned u = __float_as_uint(f);
    return (u & 0x80000000u) ? ~u : (u | 0x80000000u);
}
__device__ inline unsigned long long packmax(float s, int row) {
    return ((unsigned long long)fmap(s) << 32) | (unsigned)(0xFFFFFFFFu - (unsigned)row);
}
__device__ inline float sigm(float v) { return 1.0f / (1.0f + expf(-v)); }

// h fragment layout "hr4": hr[j] = h4[lane + 64j] (covers all 1024)
__device__ inline void load_h4(const float* __restrict__ h, float4 hr[4], int lane) {
    const float4* h4 = (const float4*)h;
#pragma unroll
    for (int j = 0; j < 4; ++j) hr[j] = h4[lane + 64 * j];
}
// exact fp32 wave-collective row dot (hr4 layout, broadcast result)
__device__ inline float row_dot4(const float* __restrict__ Wrow,
                                 const float4 hr[4], int lane) {
    const float4* w4 = (const float4*)Wrow;
    float s = 0.f;
#pragma unroll
    for (int j = 0; j < 4; ++j) {
        float4 w = w4[lane + 64 * j];
        s = fmaf(w.x, hr[j].x, s); s = fmaf(w.y, hr[j].y, s);
        s = fmaf(w.z, hr[j].z, s); s = fmaf(w.w, hr[j].w, s);
    }
#pragma unroll
    for (int off = 32; off; off >>= 1) s += __shfl_xor(s, off, 64);
    return s;
}

// ---------------- init: states + pad SNB entries ----------------
__global__ void init_kernel(const float* __restrict__ inp,
                            float* __restrict__ x, float* __restrict__ h,
                            float* __restrict__ c, float4* __restrict__ SNB) {
    int i = threadIdx.x;  // 1024
    if (i < E_DIM) x[i] = inp[i];
    h[i] = 0.f; c[i] = 0.f;
    for (int p = i; p < VPAD - V_DIM; p += 1024)
        SNB[V_DIM + p] = make_float4(0.f, 0.f, -1e30f, 0.f);
}

// ---- gates matvec, fused with previous-step finalize ----
// doFin: 0 = x from xg; 1 = finalize from LE/pblock (i8 step); 2 = finalize from
// partials (exact f32 step-0 path).
__global__ void gatesfin_kernel(const float* __restrict__ Wih,
                                const float* __restrict__ Whh,
                                const float* __restrict__ bih,
                                const float* __restrict__ bhh,
                                const float* __restrict__ xg,
                                const float* __restrict__ h,
                                float* __restrict__ gates,
                                const float2* __restrict__ LE,
                                const float2* __restrict__ pblock,
                                const unsigned long long* __restrict__ partials,
                                const float* __restrict__ Wlin,
                                const float* __restrict__ blin,
                                const float* __restrict__ emb,
                                int* __restrict__ tok_out, int doFin) {
    const int tid = threadIdx.x, lane = tid & 63, wave = tid >> 6;  // 256 thr, 4 waves

    float4 hr[4];
    load_h4(h, hr, lane);

    __shared__ float s_wmx[4];
    __shared__ float s_M;
    __shared__ int s_nb, s_nc, s_ovf;
    __shared__ int s_blist[BL_CAP];
    __shared__ int s_clist[CAND_CAP];
    __shared__ unsigned long long s_bp[4];
    __shared__ int s_tok;

    float4 xr[2];
    if (doFin == 1) {
        // ---- finalize from int8 bounds, block-redundant (deterministic) ----
        float2 pb = pblock[tid];       // NB_LOG == blockDim == 256
        float m = pb.x;
#pragma unroll
        for (int off = 32; off; off >>= 1) m = fmaxf(m, __shfl_xor(m, off, 64));
        if (lane == 0) s_wmx[wave] = m;
        __syncthreads();
        if (tid == 0) {
            s_M = fmaxf(fmaxf(s_wmx[0], s_wmx[1]), fmaxf(s_wmx[2], s_wmx[3]));
            s_nb = 0; s_nc = 0; s_ovf = 0;
        }
        __syncthreads();
        const float M = s_M;
        if (pb.y >= M) { int p = atomicAdd(&s_nb, 1); if (p < BL_CAP) s_blist[p] = tid; else s_ovf = 1; }
        __syncthreads();
        if (!s_ovf) {
            int nb = s_nb < BL_CAP ? s_nb : BL_CAP;
            for (int ii = tid; ii < nb * RPB; ii += 256) {
                int bi = ii / RPB, off = ii - bi * RPB;
                int r = s_blist[bi] * RPB + off;
                float2 le = LE[r];
                if (le.x + le.y >= M) {
                    int p = atomicAdd(&s_nc, 1);
                    if (p < CAND_CAP) s_clist[p] = r; else s_ovf = 1;
                }
            }
        }
        __syncthreads();
        if (tid == 0 && s_nc == 0) s_ovf = 1;   // defensive
        __syncthreads();
        const int ovf = s_ovf;
        const int n = s_nc < CAND_CAP ? s_nc : CAND_CAP;

        unsigned long long bestp = 0ull;
        if (!ovf) {
            for (int ci = wave; ci < n; ci += 4) {
                int row = s_clist[ci];
                float s = row_dot4(Wlin + (size_t)row * H_DIM, hr, lane) + blin[row];
                unsigned long long p = packmax(s, row);
                if (p > bestp) bestp = p;
            }
        } else {  // safety net only
            for (int row = wave; row < V_DIM; row += 4) {
                float s = row_dot4(Wlin + (size_t)row * H_DIM, hr, lane) + blin[row];
                unsigned long long p = packmax(s, row);
                if (p > bestp) bestp = p;
            }
        }
        if (lane == 0) s_bp[wave] = bestp;
        __syncthreads();
        if (tid == 0) {
            unsigned long long B = s_bp[0];
            for (int w = 1; w < 4; ++w) if (s_bp[w] > B) B = s_bp[w];
            int tok = (int)(0xFFFFFFFFu - (unsigned)(B & 0xFFFFFFFFu));
            s_tok = tok;
            *tok_out = tok;
        }
        __syncthreads();
        int tokc = s_tok;
        if (tokc < 0) tokc = 0;
        if (tokc >= V_DIM) tokc = V_DIM - 1;
        const float4* e4 = (const float4*)(emb + (size_t)tokc * E_DIM);
        xr[0] = e4[lane]; xr[1] = e4[lane + 64];
    } else if (doFin == 2) {
        // ---- finalize from exact f32 partials (step-0 tail), block-redundant ----
        unsigned long long bp = 0ull;
#pragma unroll
        for (int j = 0; j < 4; ++j) {
            unsigned long long p = partials[tid + 256 * j];
            if (p > bp) bp = p;
        }
#pragma unroll
        for (int off = 32; off; off >>= 1) {
            unsigned long long o = __shfl_xor(bp, off, 64);
            if (o > bp) bp = o;
        }
        if (lane == 0) s_bp[wave] = bp;
        __syncthreads();
        if (tid == 0) {
            unsigned long long B = s_bp[0];
            for (int w = 1; w < 4; ++w) if (s_bp[w] > B) B = s_bp[w];
            int tok = (int)(0xFFFFFFFFu - (unsigned)(B & 0xFFFFFFFFu));
            s_tok = tok;
            *tok_out = tok;
        }
        __syncthreads();
        int tokc = s_tok;
        if (tokc < 0) tokc = 0;
        if (tokc >= V_DIM) tokc = V_DIM - 1;
        const float4* e4 = (const float4*)(emb + (size_t)tokc * E_DIM);
        xr[0] = e4[lane]; xr[1] = e4[lane + 64];
    } else {
        const float4* x4 = (const float4*)xg;
        xr[0] = x4[lane]; xr[1] = x4[lane + 64];
    }

    // ---- gates matvec: 4096 rows over 1024 waves ----
    for (int row = blockIdx.x * 4 + wave; row < 4 * H_DIM; row += NB_GATES * 4) {
        const float4* wi = (const float4*)(Wih + (size_t)row * E_DIM);
        const float4* wh = (const float4*)(Whh + (size_t)row * H_DIM);
        float s = 0.f;
#pragma unroll
        for (int j = 0; j < 2; ++j) {
            float4 w = wi[lane + j * 64];
            s = fmaf(w.x, xr[j].x, s); s = fmaf(w.y, xr[j].y, s);
            s = fmaf(w.z, xr[j].z, s); s = fmaf(w.w, xr[j].w, s);
        }
#pragma unroll
        for (int j = 0; j < 4; ++j) {
            float4 w = wh[lane + j * 64];
            s = fmaf(w.x, hr[j].x, s); s = fmaf(w.y, hr[j].y, s);
            s = fmaf(w.z, hr[j].z, s); s = fmaf(w.w, hr[j].w, s);
        }
#pragma unroll
        for (int off = 32; off; off >>= 1) s += __shfl_xor(s, off, 64);
        if (lane == 0) gates[row] = s + bih[row] + bhh[row];
    }
}

// -------- step-0: fused cell + fp32 logits + int8 convert --------
__global__ void logits_f32_kernel(const float* __restrict__ Wlin,
                                  const float* __restrict__ blin,
                                  const float* __restrict__ gates,
                                  const float* __restrict__ cin,
                                  float* __restrict__ cout,
                                  float* __restrict__ hout,
                                  uint4* __restrict__ WbI,
                                  float4* __restrict__ SNB, int doConv,
                                  unsigned long long* __restrict__ partials) {
    const int tid = threadIdx.x, lane = tid & 63, wave = tid >> 6;  // 256 thr
    const int gw = blockIdx.x * 4 + wave;

    __shared__ float h_lds[H_DIM];
    {
        // fused LSTM cell: thread t computes float4 t (256 float4s)
        const float4* g4i = (const float4*)gates;
        const float4* g4f = (const float4*)(gates + H_DIM);
        const float4* g4g = (const float4*)(gates + 2 * H_DIM);
        const float4* g4o = (const float4*)(gates + 3 * H_DIM);
        const float4* c4  = (const float4*)cin;
        float4 gi = g4i[tid], gf = g4f[tid], gg = g4g[tid], go = g4o[tid], cc = c4[tid];
        float4 hv, cv;
        cv.x = sigm(gf.x) * cc.x + sigm(gi.x) * tanhf(gg.x);
        cv.y = sigm(gf.y) * cc.y + sigm(gi.y) * tanhf(gg.y);
        cv.z = sigm(gf.z) * cc.z + sigm(gi.z) * tanhf(gg.z);
        cv.w = sigm(gf.w) * cc.w + sigm(gi.w) * tanhf(gg.w);
        hv.x = sigm(go.x) * tanhf(cv.x);
        hv.y = sigm(go.y) * tanhf(cv.y);
        hv.z = sigm(go.z) * tanhf(cv.z);
        hv.w = sigm(go.w) * tanhf(cv.w);
        ((float4*)h_lds)[tid] = hv;
        if (blockIdx.x == 0) {
            ((float4*)hout)[tid] = hv;
            ((float4*)cout)[tid] = cv;
        }
    }
    __syncthreads();

    float4 hr[4];
#pragma unroll
    for (int j = 0; j < 4; ++j) hr[j] = ((const float4*)h_lds)[lane + 64 * j];

    float best = -INFINITY;
    int bidx = 0x7fffffff;
    for (int row = gw; row < V_DIM; row += NB_F32 * 4) {
        const float4* w4 = (const float4*)(Wlin + (size_t)row * H_DIM);
        float4 A[4];
#pragma unroll
        for (int j = 0; j < 4; ++j) A[j] = w4[lane + 64 * j];

        float s = 0.f, mx = 0.f;
#pragma unroll
        for (int j = 0; j < 4; ++j) {
            s = fmaf(A[j].x, hr[j].x, s); s = fmaf(A[j].y, hr[j].y, s);
            s = fmaf(A[j].z, hr[j].z, s); s = fmaf(A[j].w, hr[j].w, s);
            mx = fmaxf(mx, fmaxf(fmaxf(fabsf(A[j].x), fabsf(A[j].y)),
                                 fmaxf(fabsf(A[j].z), fabsf(A[j].w))));
        }
#pragma unroll
        for (int off = 32; off; off >>= 1) {
            s += __shfl_xor(s, off, 64);
            mx = fmaxf(mx, __shfl_xor(mx, off, 64));
        }

        if (doConv) {
            float scale = mx * (1.0f / 127.0f);
            float inv = (mx > 0.f) ? (127.0f / mx) : 0.f;
            float d2 = 0.f;
            unsigned pw[4];
#pragma unroll
            for (int j = 0; j < 4; ++j) {
                float q0 = fminf(fmaxf(rintf(A[j].x * inv), -127.f), 127.f);
                float q1 = fminf(fmaxf(rintf(A[j].y * inv), -127.f), 127.f);
                float q2 = fminf(fmaxf(rintf(A[j].z * inv), -127.f), 127.f);
                float q3 = fminf(fmaxf(rintf(A[j].w * inv), -127.f), 127.f);
                float r0 = A[j].x - q0 * scale;
                float r1 = A[j].y - q1 * scale;
                float r2 = A[j].z - q2 * scale;
                float r3 = A[j].w - q3 * scale;
                d2 = fmaf(r0, r0, d2); d2 = fmaf(r1, r1, d2);
                d2 = fmaf(r2, r2, d2); d2 = fmaf(r3, r3, d2);
                pw[j] = ((unsigned)(int)q0 & 0xFFu) | (((unsigned)(int)q1 & 0xFFu) << 8) |
                        (((unsigned)(int)q2 & 0xFFu) << 16) | (((unsigned)(int)q3 & 0xFFu) << 24);
            }
#pragma unroll
            for (int off = 32; off; off >>= 1) d2 += __shfl_xor(d2, off, 64);
            WbI[(size_t)row * 64 + lane] = make_uint4(pw[0], pw[1], pw[2], pw[3]);
            if (lane == 0)
                SNB[row] = make_float4(scale, sqrtf(d2) + 3e-3f * mx, blin[row], 0.f);
        }
        s += blin[row];
        if (s > best) { best = s; bidx = row; }
    }

    __shared__ float bv[4];
    __shared__ int bi[4];
    if (lane == 0) { bv[wave] = best; bi[wave] = bidx; }
    __syncthreads();
    if (tid == 0) {
        float B = bv[0]; int I = bi[0];
        for (int w = 1; w < 4; ++w)
            if (bv[w] > B || (bv[w] == B && bi[w] < I)) { B = bv[w]; I = bi[w]; }
        partials[blockIdx.x] = packmax(B, I);
    }
}

// ------- int8 scan: full preload + all-wave scalar cell, padded domain -------
__global__ __launch_bounds__(1024, 4)
void logits_i8_kernel(const uint4* __restrict__ WbI,
                      const float4* __restrict__ SNB,
                      const float* __restrict__ gates,
                      const float* __restrict__ cin,
                      float* __restrict__ cout,
                      float* __restrict__ hout,
                      float2* __restrict__ LE,
                      float2* __restrict__ pblock) {
    const int tid = threadIdx.x, lane = tid & 63, wave = tid >> 6;  // 16 waves
    const int wid = blockIdx.x * 16 + wave;
    const int r0 = wid * RPW;

    // full preload: 13 static uint4 loads, all in flight before the cell
    const uint4* rb = WbI + (size_t)r0 * 64 + lane;
    uint4 wq[RPW];
#pragma unroll
    for (int k = 0; k < RPW; ++k) wq[k] = rb[(size_t)k * 64];

    __shared__ float h_lds[H_DIM];
    __shared__ float ws[16];

    {   // scalar cell: all 1024 threads, one element each
        float gi = gates[tid];
        float gf = gates[tid + H_DIM];
        float gg = gates[tid + 2 * H_DIM];
        float go = gates[tid + 3 * H_DIM];
        float cc = cin[tid];
        float cv = sigm(gf) * cc + sigm(gi) * tanhf(gg);
        float hv = sigm(go) * tanhf(cv);
        h_lds[tid] = hv;
        if (blockIdx.x == 0) { hout[tid] = hv; cout[tid] = cv; }
        float sq = hv * hv;
#pragma unroll
        for (int off = 32; off; off >>= 1) sq += __shfl_xor(sq, off, 64);
        if (lane == 0) ws[wave] = sq;
    }
    __syncthreads();
    // fixed-order sum -> identical K in every block/thread
    float k2 = ws[0];
#pragma unroll
    for (int w = 1; w < 16; ++w) k2 += ws[w];
    const float K = sqrtf(k2);

    float4 hr[4];
#pragma unroll
    for (int j = 0; j < 4; ++j) hr[j] = ((const float4*)h_lds)[lane + 64 * j];

    float maxl = -INFINITY, maxu = -INFINITY;
#pragma unroll
    for (int k = 0; k < RPW; ++k) {
        uint4 c = wq[k];
        float s = 0.f;
        {
            int v = (int)c.x;
            s = fmaf((float)((v << 24) >> 24), hr[0].x, s);
            s = fmaf((float)((v << 16) >> 24), hr[0].y, s);
            s = fmaf((float)((v << 8) >> 24),  hr[0].z, s);
            s = fmaf((float)(v >> 24),         hr[0].w, s);
        }
        {
            int v = (int)c.y;
            s = fmaf((float)((v << 24) >> 24), hr[1].x, s);
            s = fmaf((float)((v << 16) >> 24), hr[1].y, s);
            s = fmaf((float)((v << 8) >> 24),  hr[1].z, s);
            s = fmaf((float)(v >> 24),         hr[1].w, s);
        }
        {
            int v = (int)c.z;
            s = fmaf((float)((v << 24) >> 24), hr[2].x, s);
            s = fmaf((float)((v << 16) >> 24), hr[2].y, s);
            s = fmaf((float)((v << 8) >> 24),  hr[2].z, s);
            s = fmaf((float)(v >> 24),         hr[2].w, s);
        }
        {
            int v = (int)c.w;
            s = fmaf((float)((v << 24) >> 24), hr[3].x, s);
            s = fmaf((float)((v << 16) >> 24), hr[3].y, s);
            s = fmaf((float)((v << 8) >> 24),  hr[3].z, s);
            s = fmaf((float)(v >> 24),         hr[3].w, s);
        }
#pragma unroll
        for (int off = 32; off; off >>= 1) s += __shfl_xor(s, off, 64);
        int r = r0 + k;
        float4 snb = SNB[r];
        float L = fmaf(snb.x, s, snb.z);
        float e = fmaf(snb.y, K, 1e-6f);
        if (lane == 0) LE[r] = make_float2(L, e);
        maxl = fmaxf(maxl, L - e);
        maxu = fmaxf(maxu, L + e);
    }

    __shared__ float wl[16], wu[16];
    if (lane == 0) { wl[wave] = maxl; wu[wave] = maxu; }
    __syncthreads();
    if (tid == 0) {
        float lo = wl[0], up = wu[0];
        for (int w = 1; w < 16; ++w) { lo = fmaxf(lo, wl[w]); up = fmaxf(up, wu[w]); }
        pblock[blockIdx.x] = make_float2(lo, up);
    }
}

// ------- f32-path tail finalize (writes token + x) -------
__global__ void finalize_f32_kernel(const unsigned long long* __restrict__ partials,
                                    const float* __restrict__ emb,
                                    float* __restrict__ x, int* __restrict__ tok_out) {
    const int lane = threadIdx.x & 63, wave = threadIdx.x >> 6;
    unsigned long long best = 0ull;
    for (int i = threadIdx.x; i < NB_F32; i += 256) {
        unsigned long long p = partials[i];
        if (p > best) best = p;
    }
#pragma unroll
    for (int off = 32; off; off >>= 1) {
        unsigned long long o = __shfl_xor(best, off, 64);
        if (o > best) best = o;
    }
    __shared__ unsigned long long sb[4];
    __shared__ int stok;
    if (lane == 0) sb[wave] = best;
    __syncthreads();
    if (threadIdx.x == 0) {
        unsigned long long B = sb[0];
        for (int w = 1; w < 4; ++w) if (sb[w] > B) B = sb[w];
        int tok = (int)(0xFFFFFFFFu - (unsigned)(B & 0xFFFFFFFFu));
        *tok_out = tok;
        stok = tok;
    }
    __syncthreads();
    int tok = stok;
    if (tok < 0) tok = 0;
    if (tok >= V_DIM) tok = V_DIM - 1;
    const float4* e4 = (const float4*)(emb + (size_t)tok * E_DIM);
    float4* x4 = (float4*)x;
    if (threadIdx.x < E_DIM / 4) x4[threadIdx.x] = e4[threadIdx.x];
}

// ------- standalone tail finalize (last i8 step) -------
__global__ void finalize_tail_kernel(const float2* __restrict__ LE,
                                     const float2* __restrict__ pblock,
                                     const float* __restrict__ Wlin,
                                     const float* __restrict__ blin,
                                     const float* __restrict__ h,
                                     const float* __restrict__ emb,
                                     float* __restrict__ x, int* __restrict__ tok_out) {
    const int tid = threadIdx.x;              // 1024 threads
    const int lane = tid & 63, wv = tid >> 6; // 16 waves

    __shared__ float wmx[16];
    __shared__ float sM;
    __shared__ int snb, sncand, sovf;
    __shared__ int blist[BL_CAP];
    __shared__ int clist[CAND_CAP];

    float2 pb = make_float2(-INFINITY, -INFINITY);
    if (tid < NB_LOG) pb = pblock[tid];
    float m = pb.x;
#pragma unroll
    for (int off = 32; off; off >>= 1) m = fmaxf(m, __shfl_xor(m, off, 64));
    if (lane == 0) wmx[wv] = m;
    __syncthreads();
    if (tid == 0) {
        float M = wmx[0];
        for (int w = 1; w < 16; ++w) M = fmaxf(M, wmx[w]);
        sM = M; snb = 0; sncand = 0; sovf = 0;
    }
    __syncthreads();
    const float M = sM;

    if (tid < NB_LOG && pb.y >= M) {
        int p = atomicAdd(&snb, 1);
        if (p < BL_CAP) blist[p] = tid; else sovf = 1;
    }
    __syncthreads();
    if (!sovf) {
        int nb = snb < BL_CAP ? snb : BL_CAP;
        for (int ii = tid; ii < nb * RPB; ii += 1024) {
            int bi = ii / RPB, off = ii - bi * RPB;
            int r = blist[bi] * RPB + off;
            float2 le = LE[r];
            if (le.x + le.y >= M) {
                int p = atomicAdd(&sncand, 1);
                if (p < CAND_CAP) clist[p] = r; else sovf = 1;
            }
        }
    }
    __syncthreads();
    if (tid == 0 && sncand == 0) sovf = 1;
    __syncthreads();
    const int ovf = sovf;
    const int n = sncand < CAND_CAP ? sncand : CAND_CAP;

    float4 hr[4];
    load_h4(h, hr, lane);
    unsigned long long bestp = 0ull;
    if (!ovf) {
        for (int ci = wv; ci < n; ci += 16) {
            int row = clist[ci];
            float s = row_dot4(Wlin + (size_t)row * H_DIM, hr, lane) + blin[row];
            unsigned long long p = packmax(s, row);
            if (p > bestp) bestp = p;
        }
    } else {
        for (int row = wv; row < V_DIM; row += 16) {
            float s = row_dot4(Wlin + (size_t)row * H_DIM, hr, lane) + blin[row];
            unsigned long long p = packmax(s, row);
            if (p > bestp) bestp = p;
        }
    }
    __shared__ unsigned long long sbp[16];
    __shared__ int stok;
    if (lane == 0) sbp[wv] = bestp;
    __syncthreads();
    if (tid == 0) {
        unsigned long long B = sbp[0];
        for (int w = 1; w < 16; ++w) if (sbp[w] > B) B = sbp[w];
        int tok = (int)(0xFFFFFFFFu - (unsigned)(B & 0xFFFFFFFFu));
        stok = tok;
        *tok_out = tok;
    }
    __syncthreads();
    int tok = stok;
    if (tok < 0) tok = 0;
    if (tok >= V_DIM) tok = V_DIM - 1;
    const float4* e4 = (const float4*)(emb + (size_t)tok * E_DIM);
    float4* xo = (float4*)x;
    if (tid < E_DIM / 4) xo[tid] = e4[tid];
}

extern "C" void kernel_launch(void* const* d_in, const int* in_sizes, int n_in,
                              void* d_out, int out_size, void* d_ws, size_t ws_size,
                              hipStream_t stream) {
    const float* inp  = (const float*)d_in[0];
    const float* Wih  = (const float*)d_in[1];
    const float* Whh  = (const float*)d_in[2];
    const float* bih  = (const float*)d_in[3];
    const float* bhh  = (const float*)d_in[4];
    const float* emb  = (const float*)d_in[5];
    const float* Wlin = (const float*)d_in[6];
    const float* blin = (const float*)d_in[7];
    int* toks = (int*)d_out;

    char* ws = (char*)d_ws;
    float* x     = (float*)(ws + OFF_X);
    float* h     = (float*)(ws + OFF_H);
    float* c0b   = (float*)(ws + OFF_C);
    float* c1b   = (float*)(ws + OFF_C2);
    float* gates = (float*)(ws + OFF_GATES);
    unsigned long long* partials = (unsigned long long*)(ws + OFF_PART);
    float2* pblock = (float2*)(ws + OFF_PBLOCK);
    float4* SNB  = (float4*)(ws + OFF_SNB);
    float2* LE   = (float2*)(ws + OFF_LE);
    uint4* WbI   = (uint4*)(ws + OFF_WBI);

    const int useI8 = (ws_size >= WS_NEEDED) ? 1 : 0;

    init_kernel<<<1, 1024, 0, stream>>>(inp, x, h, c0b, SNB);

    if (!useI8) {
        for (int step = 0; step < NSTEPS; ++step) {
            gatesfin_kernel<<<NB_GATES, 256, 0, stream>>>(
                Wih, Whh, bih, bhh, x, h, gates, LE, pblock, partials,
                Wlin, blin, emb,
                (step >= 1) ? (toks + step - 1) : (int*)nullptr, (step >= 1) ? 2 : 0);
            logits_f32_kernel<<<NB_F32, 256, 0, stream>>>(
                Wlin, blin, gates, c0b, c0b, h, WbI, SNB, 0, partials);
        }
        finalize_f32_kernel<<<1, 256, 0, stream>>>(partials, emb, x, toks + NSTEPS - 1);
        return;
    }

    // ---- step 0: gates + fused-cell fp32 scan + int8 conversion ----
    gatesfin_kernel<<<NB_GATES, 256, 0, stream>>>(
        Wih, Whh, bih, bhh, x, h, gates, LE, pblock, partials,
        Wlin, blin, emb, (int*)nullptr, 0);
    logits_f32_kernel<<<NB_F32, 256, 0, stream>>>(
        Wlin, blin, gates, c0b, c0b, h, WbI, SNB, 1, partials);

    // ---- steps 1..18: 2 kernels per step ----
    for (int t = 1; t < NSTEPS; ++t) {
        // t==1: finalize step 0 from exact f32 partials (mode 2);
        // t>=2: finalize step t-1 from int8 bounds (mode 1)
        gatesfin_kernel<<<NB_GATES, 256, 0, stream>>>(
            Wih, Whh, bih, bhh, x, h, gates, LE, pblock, partials,
            Wlin, blin, emb, toks + t - 1, (t == 1) ? 2 : 1);
        float* cin  = (t & 1) ? c0b : c1b;   // t=1 reads c0b (c_0)
        float* cout = (t & 1) ? c1b : c0b;
        logits_i8_kernel<<<NB_LOG, 1024, 0, stream>>>(
            WbI, SNB, gates, cin, cout, h, LE, pblock);
    }
    // tail: finalize step 18
    finalize_tail_kernel<<<1, 1024, 0, stream>>>(LE, pblock, Wlin, blin, h, emb,
                                                 x, toks + NSTEPS - 1);
}

// Round 13
// 434.740 us; speedup vs baseline: 1.1478x; 1.1478x over previous
//
#include <hip/hip_runtime.h>
#include <hip/hip_bf16.h>
#include <math.h>

#define E_DIM 512
#define H_DIM 1024
#define V_DIM 50257
#define NSTEPS 19
#define NB_F32 1024      // fp32 logits blocks (4 waves each)
#define NB_LOG 256       // int8 scan blocks (16 waves each) -> 4096 waves, 1 block/CU
#define RPW 13           // rows per wave (4096*13 = 53248 >= V)
#define RPB 208          // rows per scan block (16*13)
#define VPAD 53248       // padded row count
#define NB_GATES 256
#define BL_CAP 192
#define CAND_CAP 1024
#define PF 4             // row prefetch depth (all-static indices)

// ---- workspace layout (bytes), NO overlaps, 16B-aligned ----
#define OFF_X      0          // 512 f
#define OFF_H      4096       // 1024 f
#define OFF_C      8192       // 1024 f (ping)
#define OFF_C2     12288      // 1024 f (pong)
#define OFF_GATES  16384      // 4096 f (ends 32768)
#define OFF_PART   33024      // 1024 u64 (ends 41216)
#define OFF_PBLOCK 41216      // 256 float2 (ends 43264)
#define OFF_SNB    49152      // VPAD float4 {scale, nrm, bias, 0} (ends 901120)
#define OFF_LE     901120     // VPAD float2 {L, e} (ends 1327104)
#define OFF_WBI    1327104    // int8 W_lin, VPAD*1024 B (ends 55853056)
#define WS_NEEDED  55853056ull

__device__ inline unsigned fmap(float f) {
    unsigned u = __float_as_uint(f);
    return (u & 0x80000000u) ? ~u : (u | 0x80000000u);
}
__device__ inline unsigned long long packmax(float s, int row) {
    return ((unsigned long long)fmap(s) << 32) | (unsigned)(0xFFFFFFFFu - (unsigned)row);
}
__device__ inline float sigm(float v) { return 1.0f / (1.0f + expf(-v)); }

// h fragment layout "hr4": hr[j] = h4[lane + 64j] (covers all 1024)
__device__ inline void load_h4(const float* __restrict__ h, float4 hr[4], int lane) {
    const float4* h4 = (const float4*)h;
#pragma unroll
    for (int j = 0; j < 4; ++j) hr[j] = h4[lane + 64 * j];
}
// exact fp32 wave-collective row dot (hr4 layout, broadcast result)
__device__ inline float row_dot4(const float* __restrict__ Wrow,
                                 const float4 hr[4], int lane) {
    const float4* w4 = (const float4*)Wrow;
    float s = 0.f;
#pragma unroll
    for (int j = 0; j < 4; ++j) {
        float4 w = w4[lane + 64 * j];
        s = fmaf(w.x, hr[j].x, s); s = fmaf(w.y, hr[j].y, s);
        s = fmaf(w.z, hr[j].z, s); s = fmaf(w.w, hr[j].w, s);
    }
#pragma unroll
    for (int off = 32; off; off >>= 1) s += __shfl_xor(s, off, 64);
    return s;
}

// ---------------- init: states + pad SNB entries ----------------
__global__ void init_kernel(const float* __restrict__ inp,
                            float* __restrict__ x, float* __restrict__ h,
                            float* __restrict__ c, float4* __restrict__ SNB) {
    int i = threadIdx.x;  // 1024
    if (i < E_DIM) x[i] = inp[i];
    h[i] = 0.f; c[i] = 0.f;
    for (int p = i; p < VPAD - V_DIM; p += 1024)
        SNB[V_DIM + p] = make_float4(0.f, 0.f, -1e30f, 0.f);
}

// ---- gates matvec, fused with previous-step finalize ----
// doFin: 0 = x from xg; 1 = finalize from LE/pblock (i8 step); 2 = finalize from
// partials (exact f32 step-0 path).
__global__ void gatesfin_kernel(const float* __restrict__ Wih,
                                const float* __restrict__ Whh,
                                const float* __restrict__ bih,
                                const float* __restrict__ bhh,
                                const float* __restrict__ xg,
                                const float* __restrict__ h,
                                float* __restrict__ gates,
                                const float2* __restrict__ LE,
                                const float2* __restrict__ pblock,
                                const unsigned long long* __restrict__ partials,
                                const float* __restrict__ Wlin,
                                const float* __restrict__ blin,
                                const float* __restrict__ emb,
                                int* __restrict__ tok_out, int doFin) {
    const int tid = threadIdx.x, lane = tid & 63, wave = tid >> 6;  // 256 thr, 4 waves

    float4 hr[4];
    load_h4(h, hr, lane);

    __shared__ float s_wmx[4];
    __shared__ float s_M;
    __shared__ int s_nb, s_nc, s_ovf;
    __shared__ int s_blist[BL_CAP];
    __shared__ int s_clist[CAND_CAP];
    __shared__ unsigned long long s_bp[4];
    __shared__ int s_tok;

    float4 xr[2];
    if (doFin == 1) {
        // ---- finalize from int8 bounds, block-redundant (deterministic) ----
        float2 pb = pblock[tid];       // NB_LOG == blockDim == 256
        float m = pb.x;
#pragma unroll
        for (int off = 32; off; off >>= 1) m = fmaxf(m, __shfl_xor(m, off, 64));
        if (lane == 0) s_wmx[wave] = m;
        __syncthreads();
        if (tid == 0) {
            s_M = fmaxf(fmaxf(s_wmx[0], s_wmx[1]), fmaxf(s_wmx[2], s_wmx[3]));
            s_nb = 0; s_nc = 0; s_ovf = 0;
        }
        __syncthreads();
        const float M = s_M;
        if (pb.y >= M) { int p = atomicAdd(&s_nb, 1); if (p < BL_CAP) s_blist[p] = tid; else s_ovf = 1; }
        __syncthreads();
        if (!s_ovf) {
            int nb = s_nb < BL_CAP ? s_nb : BL_CAP;
            for (int ii = tid; ii < nb * RPB; ii += 256) {
                int bi = ii / RPB, off = ii - bi * RPB;
                int r = s_blist[bi] * RPB + off;
                float2 le = LE[r];
                if (le.x + le.y >= M) {
                    int p = atomicAdd(&s_nc, 1);
                    if (p < CAND_CAP) s_clist[p] = r; else s_ovf = 1;
                }
            }
        }
        __syncthreads();
        if (tid == 0 && s_nc == 0) s_ovf = 1;   // defensive
        __syncthreads();
        const int ovf = s_ovf;
        const int n = s_nc < CAND_CAP ? s_nc : CAND_CAP;

        unsigned long long bestp = 0ull;
        if (!ovf) {
            for (int ci = wave; ci < n; ci += 4) {
                int row = s_clist[ci];
                float s = row_dot4(Wlin + (size_t)row * H_DIM, hr, lane) + blin[row];
                unsigned long long p = packmax(s, row);
                if (p > bestp) bestp = p;
            }
        } else {  // safety net only
            for (int row = wave; row < V_DIM; row += 4) {
                float s = row_dot4(Wlin + (size_t)row * H_DIM, hr, lane) + blin[row];
                unsigned long long p = packmax(s, row);
                if (p > bestp) bestp = p;
            }
        }
        if (lane == 0) s_bp[wave] = bestp;
        __syncthreads();
        if (tid == 0) {
            unsigned long long B = s_bp[0];
            for (int w = 1; w < 4; ++w) if (s_bp[w] > B) B = s_bp[w];
            int tok = (int)(0xFFFFFFFFu - (unsigned)(B & 0xFFFFFFFFu));
            s_tok = tok;
            *tok_out = tok;
        }
        __syncthreads();
        int tokc = s_tok;
        if (tokc < 0) tokc = 0;
        if (tokc >= V_DIM) tokc = V_DIM - 1;
        const float4* e4 = (const float4*)(emb + (size_t)tokc * E_DIM);
        xr[0] = e4[lane]; xr[1] = e4[lane + 64];
    } else if (doFin == 2) {
        // ---- finalize from exact f32 partials (step-0 tail), block-redundant ----
        unsigned long long bp = 0ull;
#pragma unroll
        for (int j = 0; j < 4; ++j) {
            unsigned long long p = partials[tid + 256 * j];
            if (p > bp) bp = p;
        }
#pragma unroll
        for (int off = 32; off; off >>= 1) {
            unsigned long long o = __shfl_xor(bp, off, 64);
            if (o > bp) bp = o;
        }
        if (lane == 0) s_bp[wave] = bp;
        __syncthreads();
        if (tid == 0) {
            unsigned long long B = s_bp[0];
            for (int w = 1; w < 4; ++w) if (s_bp[w] > B) B = s_bp[w];
            int tok = (int)(0xFFFFFFFFu - (unsigned)(B & 0xFFFFFFFFu));
            s_tok = tok;
            *tok_out = tok;
        }
        __syncthreads();
        int tokc = s_tok;
        if (tokc < 0) tokc = 0;
        if (tokc >= V_DIM) tokc = V_DIM - 1;
        const float4* e4 = (const float4*)(emb + (size_t)tokc * E_DIM);
        xr[0] = e4[lane]; xr[1] = e4[lane + 64];
    } else {
        const float4* x4 = (const float4*)xg;
        xr[0] = x4[lane]; xr[1] = x4[lane + 64];
    }

    // ---- gates matvec: 4096 rows over 1024 waves ----
    for (int row = blockIdx.x * 4 + wave; row < 4 * H_DIM; row += NB_GATES * 4) {
        const float4* wi = (const float4*)(Wih + (size_t)row * E_DIM);
        const float4* wh = (const float4*)(Whh + (size_t)row * H_DIM);
        float s = 0.f;
#pragma unroll
        for (int j = 0; j < 2; ++j) {
            float4 w = wi[lane + j * 64];
            s = fmaf(w.x, xr[j].x, s); s = fmaf(w.y, xr[j].y, s);
            s = fmaf(w.z, xr[j].z, s); s = fmaf(w.w, xr[j].w, s);
        }
#pragma unroll
        for (int j = 0; j < 4; ++j) {
            float4 w = wh[lane + j * 64];
            s = fmaf(w.x, hr[j].x, s); s = fmaf(w.y, hr[j].y, s);
            s = fmaf(w.z, hr[j].z, s); s = fmaf(w.w, hr[j].w, s);
        }
#pragma unroll
        for (int off = 32; off; off >>= 1) s += __shfl_xor(s, off, 64);
        if (lane == 0) gates[row] = s + bih[row] + bhh[row];
    }
}

// -------- step-0: fused cell + fp32 logits + int8 convert --------
__global__ void logits_f32_kernel(const float* __restrict__ Wlin,
                                  const float* __restrict__ blin,
                                  const float* __restrict__ gates,
                                  const float* __restrict__ cin,
                                  float* __restrict__ cout,
                                  float* __restrict__ hout,
                                  uint4* __restrict__ WbI,
                                  float4* __restrict__ SNB, int doConv,
                                  unsigned long long* __restrict__ partials) {
    const int tid = threadIdx.x, lane = tid & 63, wave = tid >> 6;  // 256 thr
    const int gw = blockIdx.x * 4 + wave;

    __shared__ float h_lds[H_DIM];
    {
        // fused LSTM cell: thread t computes float4 t (256 float4s)
        const float4* g4i = (const float4*)gates;
        const float4* g4f = (const float4*)(gates + H_DIM);
        const float4* g4g = (const float4*)(gates + 2 * H_DIM);
        const float4* g4o = (const float4*)(gates + 3 * H_DIM);
        const float4* c4  = (const float4*)cin;
        float4 gi = g4i[tid], gf = g4f[tid], gg = g4g[tid], go = g4o[tid], cc = c4[tid];
        float4 hv, cv;
        cv.x = sigm(gf.x) * cc.x + sigm(gi.x) * tanhf(gg.x);
        cv.y = sigm(gf.y) * cc.y + sigm(gi.y) * tanhf(gg.y);
        cv.z = sigm(gf.z) * cc.z + sigm(gi.z) * tanhf(gg.z);
        cv.w = sigm(gf.w) * cc.w + sigm(gi.w) * tanhf(gg.w);
        hv.x = sigm(go.x) * tanhf(cv.x);
        hv.y = sigm(go.y) * tanhf(cv.y);
        hv.z = sigm(go.z) * tanhf(cv.z);
        hv.w = sigm(go.w) * tanhf(cv.w);
        ((float4*)h_lds)[tid] = hv;
        if (blockIdx.x == 0) {
            ((float4*)hout)[tid] = hv;
            ((float4*)cout)[tid] = cv;
        }
    }
    __syncthreads();

    float4 hr[4];
#pragma unroll
    for (int j = 0; j < 4; ++j) hr[j] = ((const float4*)h_lds)[lane + 64 * j];

    float best = -INFINITY;
    int bidx = 0x7fffffff;
    for (int row = gw; row < V_DIM; row += NB_F32 * 4) {
        const float4* w4 = (const float4*)(Wlin + (size_t)row * H_DIM);
        float4 A[4];
#pragma unroll
        for (int j = 0; j < 4; ++j) A[j] = w4[lane + 64 * j];

        float s = 0.f, mx = 0.f;
#pragma unroll
        for (int j = 0; j < 4; ++j) {
            s = fmaf(A[j].x, hr[j].x, s); s = fmaf(A[j].y, hr[j].y, s);
            s = fmaf(A[j].z, hr[j].z, s); s = fmaf(A[j].w, hr[j].w, s);
            mx = fmaxf(mx, fmaxf(fmaxf(fabsf(A[j].x), fabsf(A[j].y)),
                                 fmaxf(fabsf(A[j].z), fabsf(A[j].w))));
        }
#pragma unroll
        for (int off = 32; off; off >>= 1) {
            s += __shfl_xor(s, off, 64);
            mx = fmaxf(mx, __shfl_xor(mx, off, 64));
        }

        if (doConv) {
            float scale = mx * (1.0f / 127.0f);
            float inv = (mx > 0.f) ? (127.0f / mx) : 0.f;
            float d2 = 0.f;
            unsigned pw[4];
#pragma unroll
            for (int j = 0; j < 4; ++j) {
                float q0 = fminf(fmaxf(rintf(A[j].x * inv), -127.f), 127.f);
                float q1 = fminf(fmaxf(rintf(A[j].y * inv), -127.f), 127.f);
                float q2 = fminf(fmaxf(rintf(A[j].z * inv), -127.f), 127.f);
                float q3 = fminf(fmaxf(rintf(A[j].w * inv), -127.f), 127.f);
                float r0 = A[j].x - q0 * scale;
                float r1 = A[j].y - q1 * scale;
                float r2 = A[j].z - q2 * scale;
                float r3 = A[j].w - q3 * scale;
                d2 = fmaf(r0, r0, d2); d2 = fmaf(r1, r1, d2);
                d2 = fmaf(r2, r2, d2); d2 = fmaf(r3, r3, d2);
                pw[j] = ((unsigned)(int)q0 & 0xFFu) | (((unsigned)(int)q1 & 0xFFu) << 8) |
                        (((unsigned)(int)q2 & 0xFFu) << 16) | (((unsigned)(int)q3 & 0xFFu) << 24);
            }
#pragma unroll
            for (int off = 32; off; off >>= 1) d2 += __shfl_xor(d2, off, 64);
            WbI[(size_t)row * 64 + lane] = make_uint4(pw[0], pw[1], pw[2], pw[3]);
            if (lane == 0)
                SNB[row] = make_float4(scale, sqrtf(d2) + 3e-3f * mx, blin[row], 0.f);
        }
        s += blin[row];
        if (s > best) { best = s; bidx = row; }
    }

    __shared__ float bv[4];
    __shared__ int bi[4];
    if (lane == 0) { bv[wave] = best; bi[wave] = bidx; }
    __syncthreads();
    if (tid == 0) {
        float B = bv[0]; int I = bi[0];
        for (int w = 1; w < 4; ++w)
            if (bv[w] > B || (bv[w] == B && bi[w] < I)) { B = bv[w]; I = bi[w]; }
        partials[blockIdx.x] = packmax(B, I);
    }
}

// ------- int8 scan with cooperative (LDS) fused LSTM cell (round-10 proven form) -------
// 1024 threads = 16 waves, 1 block/CU; waves 0-3 compute h,c into LDS; all consume.
// Every wave does exactly RPW rows (pad rows carry bias=-1e30, never candidates).
__global__ void logits_i8_kernel(const uint4* __restrict__ WbI,
                                 const float4* __restrict__ SNB,
                                 const float* __restrict__ gates,
                                 const float* __restrict__ cin,
                                 float* __restrict__ cout,
                                 float* __restrict__ hout,
                                 float2* __restrict__ LE,
                                 float2* __restrict__ pblock) {
    const int tid = threadIdx.x, lane = tid & 63, wave = tid >> 6;  // 16 waves
    const int wid = blockIdx.x * 16 + wave;
    const int r0 = wid * RPW;

    // all-static prefetch: constant trip counts, no breaks -> stays in VGPRs
    const uint4* rb = WbI + (size_t)r0 * 64 + lane;
    uint4 wq[RPW];
#pragma unroll
    for (int k = 0; k < PF; ++k) wq[k] = rb[(size_t)k * 64];

    __shared__ float h_lds[H_DIM];
    __shared__ float cpart[4];

    if (wave < 4) {
        const int idx4 = wave * 64 + lane;  // float4 index 0..255
        const float4* g4i = (const float4*)gates;
        const float4* g4f = (const float4*)(gates + H_DIM);
        const float4* g4g = (const float4*)(gates + 2 * H_DIM);
        const float4* g4o = (const float4*)(gates + 3 * H_DIM);
        const float4* c4  = (const float4*)cin;
        float4 gi = g4i[idx4], gf = g4f[idx4], gg = g4g[idx4], go = g4o[idx4], cc = c4[idx4];
        float4 hv, cv;
        cv.x = sigm(gf.x) * cc.x + sigm(gi.x) * tanhf(gg.x);
        cv.y = sigm(gf.y) * cc.y + sigm(gi.y) * tanhf(gg.y);
        cv.z = sigm(gf.z) * cc.z + sigm(gi.z) * tanhf(gg.z);
        cv.w = sigm(gf.w) * cc.w + sigm(gi.w) * tanhf(gg.w);
        hv.x = sigm(go.x) * tanhf(cv.x);
        hv.y = sigm(go.y) * tanhf(cv.y);
        hv.z = sigm(go.z) * tanhf(cv.z);
        hv.w = sigm(go.w) * tanhf(cv.w);
        ((float4*)h_lds)[idx4] = hv;
        if (blockIdx.x == 0) {
            ((float4*)hout)[idx4] = hv;
            ((float4*)cout)[idx4] = cv;
        }
        float sq = fmaf(hv.x, hv.x, fmaf(hv.y, hv.y, fmaf(hv.z, hv.z, hv.w * hv.w)));
#pragma unroll
        for (int off = 32; off; off >>= 1) sq += __shfl_xor(sq, off, 64);
        if (lane == 0) cpart[wave] = sq;
    }
    __syncthreads();
    const float K = sqrtf(cpart[0] + cpart[1] + cpart[2] + cpart[3]);  // ||h||_2

    float4 hr[4];
#pragma unroll
    for (int j = 0; j < 4; ++j) hr[j] = ((const float4*)h_lds)[lane + 64 * j];

    float maxl = -INFINITY, maxu = -INFINITY;
#pragma unroll
    for (int k = 0; k < RPW; ++k) {
        if (k + PF < RPW) wq[k + PF] = rb[(size_t)(k + PF) * 64];
        uint4 c = wq[k];
        float s = 0.f;
        {
            int v = (int)c.x;
            s = fmaf((float)((v << 24) >> 24), hr[0].x, s);
            s = fmaf((float)((v << 16) >> 24), hr[0].y, s);
            s = fmaf((float)((v << 8) >> 24),  hr[0].z, s);
            s = fmaf((float)(v >> 24),         hr[0].w, s);
        }
        {
            int v = (int)c.y;
            s = fmaf((float)((v << 24) >> 24), hr[1].x, s);
            s = fmaf((float)((v << 16) >> 24), hr[1].y, s);
            s = fmaf((float)((v << 8) >> 24),  hr[1].z, s);
            s = fmaf((float)(v >> 24),         hr[1].w, s);
        }
        {
            int v = (int)c.z;
            s = fmaf((float)((v << 24) >> 24), hr[2].x, s);
            s = fmaf((float)((v << 16) >> 24), hr[2].y, s);
            s = fmaf((float)((v << 8) >> 24),  hr[2].z, s);
            s = fmaf((float)(v >> 24),         hr[2].w, s);
        }
        {
            int v = (int)c.w;
            s = fmaf((float)((v << 24) >> 24), hr[3].x, s);
            s = fmaf((float)((v << 16) >> 24), hr[3].y, s);
            s = fmaf((float)((v << 8) >> 24),  hr[3].z, s);
            s = fmaf((float)(v >> 24),         hr[3].w, s);
        }
#pragma unroll
        for (int off = 32; off; off >>= 1) s += __shfl_xor(s, off, 64);
        int r = r0 + k;
        float4 snb = SNB[r];
        float L = fmaf(snb.x, s, snb.z);
        float e = fmaf(snb.y, K, 1e-6f);
        if (lane == 0) LE[r] = make_float2(L, e);
        maxl = fmaxf(maxl, L - e);
        maxu = fmaxf(maxu, L + e);
    }

    __shared__ float wl[16], wu[16];
    if (lane == 0) { wl[wave] = maxl; wu[wave] = maxu; }
    __syncthreads();
    if (tid == 0) {
        float lo = wl[0], up = wu[0];
        for (int w = 1; w < 16; ++w) { lo = fmaxf(lo, wl[w]); up = fmaxf(up, wu[w]); }
        pblock[blockIdx.x] = make_float2(lo, up);
    }
}

// ------- f32-path tail finalize (writes token + x) -------
__global__ void finalize_f32_kernel(const unsigned long long* __restrict__ partials,
                                    const float* __restrict__ emb,
                                    float* __restrict__ x, int* __restrict__ tok_out) {
    const int lane = threadIdx.x & 63, wave = threadIdx.x >> 6;
    unsigned long long best = 0ull;
    for (int i = threadIdx.x; i < NB_F32; i += 256) {
        unsigned long long p = partials[i];
        if (p > best) best = p;
    }
#pragma unroll
    for (int off = 32; off; off >>= 1) {
        unsigned long long o = __shfl_xor(best, off, 64);
        if (o > best) best = o;
    }
    __shared__ unsigned long long sb[4];
    __shared__ int stok;
    if (lane == 0) sb[wave] = best;
    __syncthreads();
    if (threadIdx.x == 0) {
        unsigned long long B = sb[0];
        for (int w = 1; w < 4; ++w) if (sb[w] > B) B = sb[w];
        int tok = (int)(0xFFFFFFFFu - (unsigned)(B & 0xFFFFFFFFu));
        *tok_out = tok;
        stok = tok;
    }
    __syncthreads();
    int tok = stok;
    if (tok < 0) tok = 0;
    if (tok >= V_DIM) tok = V_DIM - 1;
    const float4* e4 = (const float4*)(emb + (size_t)tok * E_DIM);
    float4* x4 = (float4*)x;
    if (threadIdx.x < E_DIM / 4) x4[threadIdx.x] = e4[threadIdx.x];
}

// ------- standalone tail finalize (last i8 step) -------
__global__ void finalize_tail_kernel(const float2* __restrict__ LE,
                                     const float2* __restrict__ pblock,
                                     const float* __restrict__ Wlin,
                                     const float* __restrict__ blin,
                                     const float* __restrict__ h,
                                     const float* __restrict__ emb,
                                     float* __restrict__ x, int* __restrict__ tok_out) {
    const int tid = threadIdx.x;              // 1024 threads
    const int lane = tid & 63, wv = tid >> 6; // 16 waves

    __shared__ float wmx[16];
    __shared__ float sM;
    __shared__ int snb, sncand, sovf;
    __shared__ int blist[BL_CAP];
    __shared__ int clist[CAND_CAP];

    float2 pb = make_float2(-INFINITY, -INFINITY);
    if (tid < NB_LOG) pb = pblock[tid];
    float m = pb.x;
#pragma unroll
    for (int off = 32; off; off >>= 1) m = fmaxf(m, __shfl_xor(m, off, 64));
    if (lane == 0) wmx[wv] = m;
    __syncthreads();
    if (tid == 0) {
        float M = wmx[0];
        for (int w = 1; w < 16; ++w) M = fmaxf(M, wmx[w]);
        sM = M; snb = 0; sncand = 0; sovf = 0;
    }
    __syncthreads();
    const float M = sM;

    if (tid < NB_LOG && pb.y >= M) {
        int p = atomicAdd(&snb, 1);
        if (p < BL_CAP) blist[p] = tid; else sovf = 1;
    }
    __syncthreads();
    if (!sovf) {
        int nb = snb < BL_CAP ? snb : BL_CAP;
        for (int ii = tid; ii < nb * RPB; ii += 1024) {
            int bi = ii / RPB, off = ii - bi * RPB;
            int r = blist[bi] * RPB + off;
            float2 le = LE[r];
            if (le.x + le.y >= M) {
                int p = atomicAdd(&sncand, 1);
                if (p < CAND_CAP) clist[p] = r; else sovf = 1;
            }
        }
    }
    __syncthreads();
    if (tid == 0 && sncand == 0) sovf = 1;
    __syncthreads();
    const int ovf = sovf;
    const int n = sncand < CAND_CAP ? sncand : CAND_CAP;

    float4 hr[4];
    load_h4(h, hr, lane);
    unsigned long long bestp = 0ull;
    if (!ovf) {
        for (int ci = wv; ci < n; ci += 16) {
            int row = clist[ci];
            float s = row_dot4(Wlin + (size_t)row * H_DIM, hr, lane) + blin[row];
            unsigned long long p = packmax(s, row);
            if (p > bestp) bestp = p;
        }
    } else {
        for (int row = wv; row < V_DIM; row += 16) {
            float s = row_dot4(Wlin + (size_t)row * H_DIM, hr, lane) + blin[row];
            unsigned long long p = packmax(s, row);
            if (p > bestp) bestp = p;
        }
    }
    __shared__ unsigned long long sbp[16];
    __shared__ int stok;
    if (lane == 0) sbp[wv] = bestp;
    __syncthreads();
    if (tid == 0) {
        unsigned long long B = sbp[0];
        for (int w = 1; w < 16; ++w) if (sbp[w] > B) B = sbp[w];
        int tok = (int)(0xFFFFFFFFu - (unsigned)(B & 0xFFFFFFFFu));
        stok = tok;
        *tok_out = tok;
    }
    __syncthreads();
    int tok = stok;
    if (tok < 0) tok = 0;
    if (tok >= V_DIM) tok = V_DIM - 1;
    const float4* e4 = (const float4*)(emb + (size_t)tok * E_DIM);
    float4* xo = (float4*)x;
    if (tid < E_DIM / 4) xo[tid] = e4[tid];
}

extern "C" void kernel_launch(void* const* d_in, const int* in_sizes, int n_in,
                              void* d_out, int out_size, void* d_ws, size_t ws_size,
                              hipStream_t stream) {
    const float* inp  = (const float*)d_in[0];
    const float* Wih  = (const float*)d_in[1];
    const float* Whh  = (const float*)d_in[2];
    const float* bih  = (const float*)d_in[3];
    const float* bhh  = (const float*)d_in[4];
    const float* emb  = (const float*)d_in[5];
    const float* Wlin = (const float*)d_in[6];
    const float* blin = (const float*)d_in[7];
    int* toks = (int*)d_out;

    char* ws = (char*)d_ws;
    float* x     = (float*)(ws + OFF_X);
    float* h     = (float*)(ws + OFF_H);
    float* c0b   = (float*)(ws + OFF_C);
    float* c1b   = (float*)(ws + OFF_C2);
    float* gates = (float*)(ws + OFF_GATES);
    unsigned long long* partials = (unsigned long long*)(ws + OFF_PART);
    float2* pblock = (float2*)(ws + OFF_PBLOCK);
    float4* SNB  = (float4*)(ws + OFF_SNB);
    float2* LE   = (float2*)(ws + OFF_LE);
    uint4* WbI   = (uint4*)(ws + OFF_WBI);

    const int useI8 = (ws_size >= WS_NEEDED) ? 1 : 0;

    init_kernel<<<1, 1024, 0, stream>>>(inp, x, h, c0b, SNB);

    if (!useI8) {
        for (int step = 0; step < NSTEPS; ++step) {
            gatesfin_kernel<<<NB_GATES, 256, 0, stream>>>(
                Wih, Whh, bih, bhh, x, h, gates, LE, pblock, partials,
                Wlin, blin, emb,
                (step >= 1) ? (toks + step - 1) : (int*)nullptr, (step >= 1) ? 2 : 0);
            logits_f32_kernel<<<NB_F32, 256, 0, stream>>>(
                Wlin, blin, gates, c0b, c0b, h, WbI, SNB, 0, partials);
        }
        finalize_f32_kernel<<<1, 256, 0, stream>>>(partials, emb, x, toks + NSTEPS - 1);
        return;
    }

    // ---- step 0: gates + fused-cell fp32 scan + int8 conversion ----
    gatesfin_kernel<<<NB_GATES, 256, 0, stream>>>(
        Wih, Whh, bih, bhh, x, h, gates, LE, pblock, partials,
        Wlin, blin, emb, (int*)nullptr, 0);
    logits_f32_kernel<<<NB_F32, 256, 0, stream>>>(
        Wlin, blin, gates, c0b, c0b, h, WbI, SNB, 1, partials);

    // ---- steps 1..18: 2 kernels per step ----
    for (int t = 1; t < NSTEPS; ++t) {
        // t==1: finalize step 0 from exact f32 partials (mode 2);
        // t>=2: finalize step t-1 from int8 bounds (mode 1)
        gatesfin_kernel<<<NB_GATES, 256, 0, stream>>>(
            Wih, Whh, bih, bhh, x, h, gates, LE, pblock, partials,
            Wlin, blin, emb, toks + t - 1, (t == 1) ? 2 : 1);
        float* cin  = (t & 1) ? c0b : c1b;   // t=1 reads c0b (c_0)
        float* cout = (t & 1) ? c1b : c0b;
        logits_i8_kernel<<<NB_LOG, 1024, 0, stream>>>(
            WbI, SNB, gates, cin, cout, h, LE, pblock);
    }
    // tail: finalize step 18
    finalize_tail_kernel<<<1, 1024, 0, stream>>>(LE, pblock, Wlin, blin, h, emb,
                                                 x, toks + NSTEPS - 1);
}

// Round 14
// 417.868 us; speedup vs baseline: 1.1942x; 1.0404x over previous
//
#include <hip/hip_runtime.h>
#include <hip/hip_bf16.h>
#include <math.h>

#define E_DIM 512
#define H_DIM 1024
#define V_DIM 50257
#define NSTEPS 19
#define NB_F32 1024      // fp32 logits blocks (4 waves each)
#define NB_LOG 256       // int8 scan blocks (16 waves each) -> 4096 waves, 1 block/CU
#define RPW 13           // rows per wave (4096*13 = 53248 >= V)
#define RPB 208          // rows per scan block (16*13)
#define VPAD 53248       // padded row count
#define NB_GATES 256     // gates blocks (16 waves each -> 4096 waves, 1 row/wave)
#define BL_CAP 192
#define CAND_CAP 1024
#define PF 4             // row prefetch depth (all-static indices)

// ---- workspace layout (bytes), NO overlaps, 16B-aligned ----
#define OFF_X      0          // 512 f
#define OFF_H      4096       // 1024 f
#define OFF_C      8192       // 1024 f (ping)
#define OFF_C2     12288      // 1024 f (pong)
#define OFF_GATES  16384      // 4096 f (ends 32768)
#define OFF_PART   33024      // 1024 u64 (ends 41216)
#define OFF_PBLOCK 41216      // 256 float2 (ends 43264)
#define OFF_SNB    49152      // VPAD float4 {scale, nrm, bias, 0} (ends 901120)
#define OFF_LE     901120     // VPAD float2 {L, e} (ends 1327104)
#define OFF_WBI    1327104    // int8 W_lin, VPAD*1024 B (ends 55853056)
#define WS_NEEDED  55853056ull

__device__ inline unsigned fmap(float f) {
    unsigned u = __float_as_uint(f);
    return (u & 0x80000000u) ? ~u : (u | 0x80000000u);
}
__device__ inline unsigned long long packmax(float s, int row) {
    return ((unsigned long long)fmap(s) << 32) | (unsigned)(0xFFFFFFFFu - (unsigned)row);
}
__device__ inline float sigm(float v) { return 1.0f / (1.0f + expf(-v)); }

// h fragment layout "hr4": hr[j] = h4[lane + 64j] (covers all 1024)
__device__ inline void load_h4(const float* __restrict__ h, float4 hr[4], int lane) {
    const float4* h4 = (const float4*)h;
#pragma unroll
    for (int j = 0; j < 4; ++j) hr[j] = h4[lane + 64 * j];
}
// exact fp32 wave-collective row dot (hr4 layout, broadcast result)
__device__ inline float row_dot4(const float* __restrict__ Wrow,
                                 const float4 hr[4], int lane) {
    const float4* w4 = (const float4*)Wrow;
    float s = 0.f;
#pragma unroll
    for (int j = 0; j < 4; ++j) {
        float4 w = w4[lane + 64 * j];
        s = fmaf(w.x, hr[j].x, s); s = fmaf(w.y, hr[j].y, s);
        s = fmaf(w.z, hr[j].z, s); s = fmaf(w.w, hr[j].w, s);
    }
#pragma unroll
    for (int off = 32; off; off >>= 1) s += __shfl_xor(s, off, 64);
    return s;
}

// ---------------- init: states + pad SNB entries ----------------
__global__ void init_kernel(const float* __restrict__ inp,
                            float* __restrict__ x, float* __restrict__ h,
                            float* __restrict__ c, float4* __restrict__ SNB) {
    int i = threadIdx.x;  // 1024
    if (i < E_DIM) x[i] = inp[i];
    h[i] = 0.f; c[i] = 0.f;
    for (int p = i; p < VPAD - V_DIM; p += 1024)
        SNB[V_DIM + p] = make_float4(0.f, 0.f, -1e30f, 0.f);
}

// ---- gates matvec (1024 thr, 16 waves, 1 row/wave), fused with prev-step finalize ----
// doFin: 0 = x from xg; 1 = finalize from LE/pblock (i8 step); 2 = finalize from
// partials (exact f32 step-0 path).
__global__ void gatesfin_kernel(const float* __restrict__ Wih,
                                const float* __restrict__ Whh,
                                const float* __restrict__ bih,
                                const float* __restrict__ bhh,
                                const float* __restrict__ xg,
                                const float* __restrict__ h,
                                float* __restrict__ gates,
                                const float2* __restrict__ LE,
                                const float2* __restrict__ pblock,
                                const unsigned long long* __restrict__ partials,
                                const float* __restrict__ Wlin,
                                const float* __restrict__ blin,
                                const float* __restrict__ emb,
                                int* __restrict__ tok_out, int doFin) {
    const int tid = threadIdx.x, lane = tid & 63, wave = tid >> 6;  // 1024 thr, 16 waves

    float4 hr[4];
    load_h4(h, hr, lane);

    __shared__ float s_wmx[16];
    __shared__ float s_M;
    __shared__ int s_nb, s_nc, s_ovf;
    __shared__ int s_blist[BL_CAP];
    __shared__ int s_clist[CAND_CAP];
    __shared__ unsigned long long s_bp[16];
    __shared__ int s_tok;

    float4 xr[2];
    if (doFin == 1) {
        // ---- finalize from int8 bounds, block-redundant (deterministic) ----
        float2 pb = (tid < NB_LOG) ? pblock[tid] : make_float2(-INFINITY, -INFINITY);
        float m = pb.x;
#pragma unroll
        for (int off = 32; off; off >>= 1) m = fmaxf(m, __shfl_xor(m, off, 64));
        if (lane == 0) s_wmx[wave] = m;
        __syncthreads();
        if (tid == 0) {
            float M = s_wmx[0];
            for (int w = 1; w < 16; ++w) M = fmaxf(M, s_wmx[w]);
            s_M = M; s_nb = 0; s_nc = 0; s_ovf = 0;
        }
        __syncthreads();
        const float M = s_M;
        if (tid < NB_LOG && pb.y >= M) {
            int p = atomicAdd(&s_nb, 1);
            if (p < BL_CAP) s_blist[p] = tid; else s_ovf = 1;
        }
        __syncthreads();
        if (!s_ovf) {
            int nb = s_nb < BL_CAP ? s_nb : BL_CAP;
            for (int ii = tid; ii < nb * RPB; ii += 1024) {
                int bi = ii / RPB, off = ii - bi * RPB;
                int r = s_blist[bi] * RPB + off;
                float2 le = LE[r];
                if (le.x + le.y >= M) {
                    int p = atomicAdd(&s_nc, 1);
                    if (p < CAND_CAP) s_clist[p] = r; else s_ovf = 1;
                }
            }
        }
        __syncthreads();
        if (tid == 0 && s_nc == 0) s_ovf = 1;   // defensive
        __syncthreads();
        const int ovf = s_ovf;
        const int n = s_nc < CAND_CAP ? s_nc : CAND_CAP;

        unsigned long long bestp = 0ull;
        if (!ovf) {
            for (int ci = wave; ci < n; ci += 16) {
                int row = s_clist[ci];
                float s = row_dot4(Wlin + (size_t)row * H_DIM, hr, lane) + blin[row];
                unsigned long long p = packmax(s, row);
                if (p > bestp) bestp = p;
            }
        } else {  // safety net only
            for (int row = wave; row < V_DIM; row += 16) {
                float s = row_dot4(Wlin + (size_t)row * H_DIM, hr, lane) + blin[row];
                unsigned long long p = packmax(s, row);
                if (p > bestp) bestp = p;
            }
        }
        if (lane == 0) s_bp[wave] = bestp;
        __syncthreads();
        if (tid == 0) {
            unsigned long long B = s_bp[0];
            for (int w = 1; w < 16; ++w) if (s_bp[w] > B) B = s_bp[w];
            int tok = (int)(0xFFFFFFFFu - (unsigned)(B & 0xFFFFFFFFu));
            s_tok = tok;
            *tok_out = tok;
        }
        __syncthreads();
        int tokc = s_tok;
        if (tokc < 0) tokc = 0;
        if (tokc >= V_DIM) tokc = V_DIM - 1;
        const float4* e4 = (const float4*)(emb + (size_t)tokc * E_DIM);
        xr[0] = e4[lane]; xr[1] = e4[lane + 64];
    } else if (doFin == 2) {
        // ---- finalize from exact f32 partials (step-0 tail), block-redundant ----
        unsigned long long bp = partials[tid];   // 1024 entries == blockDim
#pragma unroll
        for (int off = 32; off; off >>= 1) {
            unsigned long long o = __shfl_xor(bp, off, 64);
            if (o > bp) bp = o;
        }
        if (lane == 0) s_bp[wave] = bp;
        __syncthreads();
        if (tid == 0) {
            unsigned long long B = s_bp[0];
            for (int w = 1; w < 16; ++w) if (s_bp[w] > B) B = s_bp[w];
            int tok = (int)(0xFFFFFFFFu - (unsigned)(B & 0xFFFFFFFFu));
            s_tok = tok;
            *tok_out = tok;
        }
        __syncthreads();
        int tokc = s_tok;
        if (tokc < 0) tokc = 0;
        if (tokc >= V_DIM) tokc = V_DIM - 1;
        const float4* e4 = (const float4*)(emb + (size_t)tokc * E_DIM);
        xr[0] = e4[lane]; xr[1] = e4[lane + 64];
    } else {
        const float4* x4 = (const float4*)xg;
        xr[0] = x4[lane]; xr[1] = x4[lane + 64];
    }

    // ---- gates matvec: 4096 rows over 4096 waves (1 row/wave, 4 waves/SIMD) ----
    for (int row = blockIdx.x * 16 + wave; row < 4 * H_DIM; row += NB_GATES * 16) {
        const float4* wi = (const float4*)(Wih + (size_t)row * E_DIM);
        const float4* wh = (const float4*)(Whh + (size_t)row * H_DIM);
        float s = 0.f;
#pragma unroll
        for (int j = 0; j < 2; ++j) {
            float4 w = wi[lane + j * 64];
            s = fmaf(w.x, xr[j].x, s); s = fmaf(w.y, xr[j].y, s);
            s = fmaf(w.z, xr[j].z, s); s = fmaf(w.w, xr[j].w, s);
        }
#pragma unroll
        for (int j = 0; j < 4; ++j) {
            float4 w = wh[lane + j * 64];
            s = fmaf(w.x, hr[j].x, s); s = fmaf(w.y, hr[j].y, s);
            s = fmaf(w.z, hr[j].z, s); s = fmaf(w.w, hr[j].w, s);
        }
#pragma unroll
        for (int off = 32; off; off >>= 1) s += __shfl_xor(s, off, 64);
        if (lane == 0) gates[row] = s + bih[row] + bhh[row];
    }
}

// -------- step-0: fused cell + fp32 logits + int8 convert --------
__global__ void logits_f32_kernel(const float* __restrict__ Wlin,
                                  const float* __restrict__ blin,
                                  const float* __restrict__ gates,
                                  const float* __restrict__ cin,
                                  float* __restrict__ cout,
                                  float* __restrict__ hout,
                                  uint4* __restrict__ WbI,
                                  float4* __restrict__ SNB, int doConv,
                                  unsigned long long* __restrict__ partials) {
    const int tid = threadIdx.x, lane = tid & 63, wave = tid >> 6;  // 256 thr
    const int gw = blockIdx.x * 4 + wave;

    __shared__ float h_lds[H_DIM];
    {
        // fused LSTM cell: thread t computes float4 t (256 float4s)
        const float4* g4i = (const float4*)gates;
        const float4* g4f = (const float4*)(gates + H_DIM);
        const float4* g4g = (const float4*)(gates + 2 * H_DIM);
        const float4* g4o = (const float4*)(gates + 3 * H_DIM);
        const float4* c4  = (const float4*)cin;
        float4 gi = g4i[tid], gf = g4f[tid], gg = g4g[tid], go = g4o[tid], cc = c4[tid];
        float4 hv, cv;
        cv.x = sigm(gf.x) * cc.x + sigm(gi.x) * tanhf(gg.x);
        cv.y = sigm(gf.y) * cc.y + sigm(gi.y) * tanhf(gg.y);
        cv.z = sigm(gf.z) * cc.z + sigm(gi.z) * tanhf(gg.z);
        cv.w = sigm(gf.w) * cc.w + sigm(gi.w) * tanhf(gg.w);
        hv.x = sigm(go.x) * tanhf(cv.x);
        hv.y = sigm(go.y) * tanhf(cv.y);
        hv.z = sigm(go.z) * tanhf(cv.z);
        hv.w = sigm(go.w) * tanhf(cv.w);
        ((float4*)h_lds)[tid] = hv;
        if (blockIdx.x == 0) {
            ((float4*)hout)[tid] = hv;
            ((float4*)cout)[tid] = cv;
        }
    }
    __syncthreads();

    float4 hr[4];
#pragma unroll
    for (int j = 0; j < 4; ++j) hr[j] = ((const float4*)h_lds)[lane + 64 * j];

    float best = -INFINITY;
    int bidx = 0x7fffffff;
    for (int row = gw; row < V_DIM; row += NB_F32 * 4) {
        const float4* w4 = (const float4*)(Wlin + (size_t)row * H_DIM);
        float4 A[4];
#pragma unroll
        for (int j = 0; j < 4; ++j) A[j] = w4[lane + 64 * j];

        float s = 0.f, mx = 0.f;
#pragma unroll
        for (int j = 0; j < 4; ++j) {
            s = fmaf(A[j].x, hr[j].x, s); s = fmaf(A[j].y, hr[j].y, s);
            s = fmaf(A[j].z, hr[j].z, s); s = fmaf(A[j].w, hr[j].w, s);
            mx = fmaxf(mx, fmaxf(fmaxf(fabsf(A[j].x), fabsf(A[j].y)),
                                 fmaxf(fabsf(A[j].z), fabsf(A[j].w))));
        }
#pragma unroll
        for (int off = 32; off; off >>= 1) {
            s += __shfl_xor(s, off, 64);
            mx = fmaxf(mx, __shfl_xor(mx, off, 64));
        }

        if (doConv) {
            float scale = mx * (1.0f / 127.0f);
            float inv = (mx > 0.f) ? (127.0f / mx) : 0.f;
            float d2 = 0.f;
            unsigned pw[4];
#pragma unroll
            for (int j = 0; j < 4; ++j) {
                float q0 = fminf(fmaxf(rintf(A[j].x * inv), -127.f), 127.f);
                float q1 = fminf(fmaxf(rintf(A[j].y * inv), -127.f), 127.f);
                float q2 = fminf(fmaxf(rintf(A[j].z * inv), -127.f), 127.f);
                float q3 = fminf(fmaxf(rintf(A[j].w * inv), -127.f), 127.f);
                float r0 = A[j].x - q0 * scale;
                float r1 = A[j].y - q1 * scale;
                float r2 = A[j].z - q2 * scale;
                float r3 = A[j].w - q3 * scale;
                d2 = fmaf(r0, r0, d2); d2 = fmaf(r1, r1, d2);
                d2 = fmaf(r2, r2, d2); d2 = fmaf(r3, r3, d2);
                pw[j] = ((unsigned)(int)q0 & 0xFFu) | (((unsigned)(int)q1 & 0xFFu) << 8) |
                        (((unsigned)(int)q2 & 0xFFu) << 16) | (((unsigned)(int)q3 & 0xFFu) << 24);
            }
#pragma unroll
            for (int off = 32; off; off >>= 1) d2 += __shfl_xor(d2, off, 64);
            WbI[(size_t)row * 64 + lane] = make_uint4(pw[0], pw[1], pw[2], pw[3]);
            if (lane == 0)
                SNB[row] = make_float4(scale, sqrtf(d2) + 3e-3f * mx, blin[row], 0.f);
        }
        s += blin[row];
        if (s > best) { best = s; bidx = row; }
    }

    __shared__ float bv[4];
    __shared__ int bi[4];
    if (lane == 0) { bv[wave] = best; bi[wave] = bidx; }
    __syncthreads();
    if (tid == 0) {
        float B = bv[0]; int I = bi[0];
        for (int w = 1; w < 4; ++w)
            if (bv[w] > B || (bv[w] == B && bi[w] < I)) { B = bv[w]; I = bi[w]; }
        partials[blockIdx.x] = packmax(B, I);
    }
}

// ------- int8 scan with cooperative (LDS) fused LSTM cell (round-10 proven form) -------
__global__ void logits_i8_kernel(const uint4* __restrict__ WbI,
                                 const float4* __restrict__ SNB,
                                 const float* __restrict__ gates,
                                 const float* __restrict__ cin,
                                 float* __restrict__ cout,
                                 float* __restrict__ hout,
                                 float2* __restrict__ LE,
                                 float2* __restrict__ pblock) {
    const int tid = threadIdx.x, lane = tid & 63, wave = tid >> 6;  // 16 waves
    const int wid = blockIdx.x * 16 + wave;
    const int r0 = wid * RPW;

    // all-static prefetch: constant trip counts, no breaks -> stays in VGPRs
    const uint4* rb = WbI + (size_t)r0 * 64 + lane;
    uint4 wq[RPW];
#pragma unroll
    for (int k = 0; k < PF; ++k) wq[k] = rb[(size_t)k * 64];

    __shared__ float h_lds[H_DIM];
    __shared__ float cpart[4];

    if (wave < 4) {
        const int idx4 = wave * 64 + lane;  // float4 index 0..255
        const float4* g4i = (const float4*)gates;
        const float4* g4f = (const float4*)(gates + H_DIM);
        const float4* g4g = (const float4*)(gates + 2 * H_DIM);
        const float4* g4o = (const float4*)(gates + 3 * H_DIM);
        const float4* c4  = (const float4*)cin;
        float4 gi = g4i[idx4], gf = g4f[idx4], gg = g4g[idx4], go = g4o[idx4], cc = c4[idx4];
        float4 hv, cv;
        cv.x = sigm(gf.x) * cc.x + sigm(gi.x) * tanhf(gg.x);
        cv.y = sigm(gf.y) * cc.y + sigm(gi.y) * tanhf(gg.y);
        cv.z = sigm(gf.z) * cc.z + sigm(gi.z) * tanhf(gg.z);
        cv.w = sigm(gf.w) * cc.w + sigm(gi.w) * tanhf(gg.w);
        hv.x = sigm(go.x) * tanhf(cv.x);
        hv.y = sigm(go.y) * tanhf(cv.y);
        hv.z = sigm(go.z) * tanhf(cv.z);
        hv.w = sigm(go.w) * tanhf(cv.w);
        ((float4*)h_lds)[idx4] = hv;
        if (blockIdx.x == 0) {
            ((float4*)hout)[idx4] = hv;
            ((float4*)cout)[idx4] = cv;
        }
        float sq = fmaf(hv.x, hv.x, fmaf(hv.y, hv.y, fmaf(hv.z, hv.z, hv.w * hv.w)));
#pragma unroll
        for (int off = 32; off; off >>= 1) sq += __shfl_xor(sq, off, 64);
        if (lane == 0) cpart[wave] = sq;
    }
    __syncthreads();
    const float K = sqrtf(cpart[0] + cpart[1] + cpart[2] + cpart[3]);  // ||h||_2

    float4 hr[4];
#pragma unroll
    for (int j = 0; j < 4; ++j) hr[j] = ((const float4*)h_lds)[lane + 64 * j];

    float maxl = -INFINITY, maxu = -INFINITY;
#pragma unroll
    for (int k = 0; k < RPW; ++k) {
        if (k + PF < RPW) wq[k + PF] = rb[(size_t)(k + PF) * 64];
        uint4 c = wq[k];
        float s = 0.f;
        {
            int v = (int)c.x;
            s = fmaf((float)((v << 24) >> 24), hr[0].x, s);
            s = fmaf((float)((v << 16) >> 24), hr[0].y, s);
            s = fmaf((float)((v << 8) >> 24),  hr[0].z, s);
            s = fmaf((float)(v >> 24),         hr[0].w, s);
        }
        {
            int v = (int)c.y;
            s = fmaf((float)((v << 24) >> 24), hr[1].x, s);
            s = fmaf((float)((v << 16) >> 24), hr[1].y, s);
            s = fmaf((float)((v << 8) >> 24),  hr[1].z, s);
            s = fmaf((float)(v >> 24),         hr[1].w, s);
        }
        {
            int v = (int)c.z;
            s = fmaf((float)((v << 24) >> 24), hr[2].x, s);
            s = fmaf((float)((v << 16) >> 24), hr[2].y, s);
            s = fmaf((float)((v << 8) >> 24),  hr[2].z, s);
            s = fmaf((float)(v >> 24),         hr[2].w, s);
        }
        {
            int v = (int)c.w;
            s = fmaf((float)((v << 24) >> 24), hr[3].x, s);
            s = fmaf((float)((v << 16) >> 24), hr[3].y, s);
            s = fmaf((float)((v << 8) >> 24),  hr[3].z, s);
            s = fmaf((float)(v >> 24),         hr[3].w, s);
        }
#pragma unroll
        for (int off = 32; off; off >>= 1) s += __shfl_xor(s, off, 64);
        int r = r0 + k;
        float4 snb = SNB[r];
        float L = fmaf(snb.x, s, snb.z);
        float e = fmaf(snb.y, K, 1e-6f);
        if (lane == 0) LE[r] = make_float2(L, e);
        maxl = fmaxf(maxl, L - e);
        maxu = fmaxf(maxu, L + e);
    }

    __shared__ float wl[16], wu[16];
    if (lane == 0) { wl[wave] = maxl; wu[wave] = maxu; }
    __syncthreads();
    if (tid == 0) {
        float lo = wl[0], up = wu[0];
        for (int w = 1; w < 16; ++w) { lo = fmaxf(lo, wl[w]); up = fmaxf(up, wu[w]); }
        pblock[blockIdx.x] = make_float2(lo, up);
    }
}

// ------- f32-path tail finalize (writes token + x) -------
__global__ void finalize_f32_kernel(const unsigned long long* __restrict__ partials,
                                    const float* __restrict__ emb,
                                    float* __restrict__ x, int* __restrict__ tok_out) {
    const int lane = threadIdx.x & 63, wave = threadIdx.x >> 6;
    unsigned long long best = 0ull;
    for (int i = threadIdx.x; i < NB_F32; i += 256) {
        unsigned long long p = partials[i];
        if (p > best) best = p;
    }
#pragma unroll
    for (int off = 32; off; off >>= 1) {
        unsigned long long o = __shfl_xor(best, off, 64);
        if (o > best) best = o;
    }
    __shared__ unsigned long long sb[4];
    __shared__ int stok;
    if (lane == 0) sb[wave] = best;
    __syncthreads();
    if (threadIdx.x == 0) {
        unsigned long long B = sb[0];
        for (int w = 1; w < 4; ++w) if (sb[w] > B) B = sb[w];
        int tok = (int)(0xFFFFFFFFu - (unsigned)(B & 0xFFFFFFFFu));
        *tok_out = tok;
        stok = tok;
    }
    __syncthreads();
    int tok = stok;
    if (tok < 0) tok = 0;
    if (tok >= V_DIM) tok = V_DIM - 1;
    const float4* e4 = (const float4*)(emb + (size_t)tok * E_DIM);
    float4* x4 = (float4*)x;
    if (threadIdx.x < E_DIM / 4) x4[threadIdx.x] = e4[threadIdx.x];
}

// ------- standalone tail finalize (last i8 step) -------
__global__ void finalize_tail_kernel(const float2* __restrict__ LE,
                                     const float2* __restrict__ pblock,
                                     const float* __restrict__ Wlin,
                                     const float* __restrict__ blin,
                                     const float* __restrict__ h,
                                     const float* __restrict__ emb,
                                     float* __restrict__ x, int* __restrict__ tok_out) {
    const int tid = threadIdx.x;              // 1024 threads
    const int lane = tid & 63, wv = tid >> 6; // 16 waves

    __shared__ float wmx[16];
    __shared__ float sM;
    __shared__ int snb, sncand, sovf;
    __shared__ int blist[BL_CAP];
    __shared__ int clist[CAND_CAP];

    float2 pb = make_float2(-INFINITY, -INFINITY);
    if (tid < NB_LOG) pb = pblock[tid];
    float m = pb.x;
#pragma unroll
    for (int off = 32; off; off >>= 1) m = fmaxf(m, __shfl_xor(m, off, 64));
    if (lane == 0) wmx[wv] = m;
    __syncthreads();
    if (tid == 0) {
        float M = wmx[0];
        for (int w = 1; w < 16; ++w) M = fmaxf(M, wmx[w]);
        sM = M; snb = 0; sncand = 0; sovf = 0;
    }
    __syncthreads();
    const float M = sM;

    if (tid < NB_LOG && pb.y >= M) {
        int p = atomicAdd(&snb, 1);
        if (p < BL_CAP) blist[p] = tid; else sovf = 1;
    }
    __syncthreads();
    if (!sovf) {
        int nb = snb < BL_CAP ? snb : BL_CAP;
        for (int ii = tid; ii < nb * RPB; ii += 1024) {
            int bi = ii / RPB, off = ii - bi * RPB;
            int r = blist[bi] * RPB + off;
            float2 le = LE[r];
            if (le.x + le.y >= M) {
                int p = atomicAdd(&sncand, 1);
                if (p < CAND_CAP) clist[p] = r; else sovf = 1;
            }
        }
    }
    __syncthreads();
    if (tid == 0 && sncand == 0) sovf = 1;
    __syncthreads();
    const int ovf = sovf;
    const int n = sncand < CAND_CAP ? sncand : CAND_CAP;

    float4 hr[4];
    load_h4(h, hr, lane);
    unsigned long long bestp = 0ull;
    if (!ovf) {
        for (int ci = wv; ci < n; ci += 16) {
            int row = clist[ci];
            float s = row_dot4(Wlin + (size_t)row * H_DIM, hr, lane) + blin[row];
            unsigned long long p = packmax(s, row);
            if (p > bestp) bestp = p;
        }
    } else {
        for (int row = wv; row < V_DIM; row += 16) {
            float s = row_dot4(Wlin + (size_t)row * H_DIM, hr, lane) + blin[row];
            unsigned long long p = packmax(s, row);
            if (p > bestp) bestp = p;
        }
    }
    __shared__ unsigned long long sbp[16];
    __shared__ int stok;
    if (lane == 0) sbp[wv] = bestp;
    __syncthreads();
    if (tid == 0) {
        unsigned long long B = sbp[0];
        for (int w = 1; w < 16; ++w) if (sbp[w] > B) B = sbp[w];
        int tok = (int)(0xFFFFFFFFu - (unsigned)(B & 0xFFFFFFFFu));
        stok = tok;
        *tok_out = tok;
    }
    __syncthreads();
    int tok = stok;
    if (tok < 0) tok = 0;
    if (tok >= V_DIM) tok = V_DIM - 1;
    const float4* e4 = (const float4*)(emb + (size_t)tok * E_DIM);
    float4* xo = (float4*)x;
    if (tid < E_DIM / 4) xo[tid] = e4[tid];
}

extern "C" void kernel_launch(void* const* d_in, const int* in_sizes, int n_in,
                              void* d_out, int out_size, void* d_ws, size_t ws_size,
                              hipStream_t stream) {
    const float* inp  = (const float*)d_in[0];
    const float* Wih  = (const float*)d_in[1];
    const float* Whh  = (const float*)d_in[2];
    const float* bih  = (const float*)d_in[3];
    const float* bhh  = (const float*)d_in[4];
    const float* emb  = (const float*)d_in[5];
    const float* Wlin = (const float*)d_in[6];
    const float* blin = (const float*)d_in[7];
    int* toks = (int*)d_out;

    char* ws = (char*)d_ws;
    float* x     = (float*)(ws + OFF_X);
    float* h     = (float*)(ws + OFF_H);
    float* c0b   = (float*)(ws + OFF_C);
    float* c1b   = (float*)(ws + OFF_C2);
    float* gates = (float*)(ws + OFF_GATES);
    unsigned long long* partials = (unsigned long long*)(ws + OFF_PART);
    float2* pblock = (float2*)(ws + OFF_PBLOCK);
    float4* SNB  = (float4*)(ws + OFF_SNB);
    float2* LE   = (float2*)(ws + OFF_LE);
    uint4* WbI   = (uint4*)(ws + OFF_WBI);

    const int useI8 = (ws_size >= WS_NEEDED) ? 1 : 0;

    init_kernel<<<1, 1024, 0, stream>>>(inp, x, h, c0b, SNB);

    if (!useI8) {
        for (int step = 0; step < NSTEPS; ++step) {
            gatesfin_kernel<<<NB_GATES, 1024, 0, stream>>>(
                Wih, Whh, bih, bhh, x, h, gates, LE, pblock, partials,
                Wlin, blin, emb,
                (step >= 1) ? (toks + step - 1) : (int*)nullptr, (step >= 1) ? 2 : 0);
            logits_f32_kernel<<<NB_F32, 256, 0, stream>>>(
                Wlin, blin, gates, c0b, c0b, h, WbI, SNB, 0, partials);
        }
        finalize_f32_kernel<<<1, 256, 0, stream>>>(partials, emb, x, toks + NSTEPS - 1);
        return;
    }

    // ---- step 0: gates + fused-cell fp32 scan + int8 conversion ----
    gatesfin_kernel<<<NB_GATES, 1024, 0, stream>>>(
        Wih, Whh, bih, bhh, x, h, gates, LE, pblock, partials,
        Wlin, blin, emb, (int*)nullptr, 0);
    logits_f32_kernel<<<NB_F32, 256, 0, stream>>>(
        Wlin, blin, gates, c0b, c0b, h, WbI, SNB, 1, partials);

    // ---- steps 1..18: 2 kernels per step ----
    for (int t = 1; t < NSTEPS; ++t) {
        // t==1: finalize step 0 from exact f32 partials (mode 2);
        // t>=2: finalize step t-1 from int8 bounds (mode 1)
        gatesfin_kernel<<<NB_GATES, 1024, 0, stream>>>(
            Wih, Whh, bih, bhh, x, h, gates, LE, pblock, partials,
            Wlin, blin, emb, toks + t - 1, (t == 1) ? 2 : 1);
        float* cin  = (t & 1) ? c0b : c1b;   // t=1 reads c0b (c_0)
        float* cout = (t & 1) ? c1b : c0b;
        logits_i8_kernel<<<NB_LOG, 1024, 0, stream>>>(
            WbI, SNB, gates, cin, cout, h, LE, pblock);
    }
    // tail: finalize step 18
    finalize_tail_kernel<<<1, 1024, 0, stream>>>(LE, pblock, Wlin, blin, h, emb,
                                                 x, toks + NSTEPS - 1);
}